// Round 6
// baseline (118812.878 us; speedup 1.0000x reference)
//
#include <hip/hip_runtime.h>
#include <math.h>

#define Bb 64
#define Ll 1024
#define Dd 512
#define G4 2048      // 4*D
#define PART_STRIDE 520

__device__ __forceinline__ float hsig(float v){ return fminf(fmaxf(0.2f*v + 0.5f, 0.f), 1.f); }

// ---------------- one-time: Wf = [Wc@Ww ; Uw]  (1536 x 2048), bf = bc@Ww + bw ----------------
// block = 16 k's x 256 j's; Ww row segment loaded once, reused for 16 k's.
__global__ __launch_bounds__(256) void wf_build(const float* __restrict__ Wc, const float* __restrict__ Ww,
                                                const float* __restrict__ Uw, float* __restrict__ Wf){
    const int k0 = (blockIdx.x >> 3) * 16;
    const int j  = (blockIdx.x & 7) * 256 + threadIdx.x;
    if (k0 < 2 * Dd){
        float acc[16];
        #pragma unroll
        for (int kk = 0; kk < 16; ++kk) acc[kk] = 0.f;
        for (int m = 0; m < Dd; ++m){
            float wv = Ww[(size_t)m * G4 + j];
            #pragma unroll
            for (int kk = 0; kk < 16; ++kk)
                acc[kk] = fmaf(Wc[(size_t)(k0 + kk) * Dd + m], wv, acc[kk]);
        }
        #pragma unroll
        for (int kk = 0; kk < 16; ++kk) Wf[(size_t)(k0 + kk) * G4 + j] = acc[kk];
    } else {
        #pragma unroll
        for (int kk = 0; kk < 16; ++kk)
            Wf[(size_t)(k0 + kk) * G4 + j] = Uw[(size_t)(k0 + kk - 2 * Dd) * G4 + j];
    }
}

__global__ __launch_bounds__(256) void bf_build(const float* __restrict__ bc, const float* __restrict__ Ww,
                                                const float* __restrict__ bw, float* __restrict__ bf){
    int j = blockIdx.x * 256 + threadIdx.x;
    float s = bw[j];
    for (int m = 0; m < Dd; ++m) s = fmaf(bc[m], Ww[(size_t)m * G4 + j], s);
    bf[j] = s;
}

// ---------------- reader gate GEMM (prologue t=0 only) ----------------
__global__ __launch_bounds__(256) void gemm_reader(const float* __restrict__ xt, const float* __restrict__ h,
                                                   const float* __restrict__ Wr, const float* __restrict__ Ur,
                                                   float* __restrict__ part){
    __shared__ float inT[64][65];
    __shared__ float wT[64][32];
    const int bx = blockIdx.x;
    const int jt = bx & 63, ks = bx >> 6;
    const int j0 = jt * 32;
    const int k0 = ks * 256;
    const int tid = threadIdx.x;
    const int tj4 = (tid & 7) * 4;
    const int tb  = tid >> 3;              // 0..31
    float a00=0.f,a01=0.f,a02=0.f,a03=0.f;
    float a10=0.f,a11=0.f,a12=0.f,a13=0.f;
    for (int kk = 0; kk < 256; kk += 64){
        #pragma unroll
        for (int i = 0; i < 16; ++i){
            int idx = tid + i * 256;
            int b = idx >> 6, k = idx & 63;
            int kg = k0 + kk + k;
            inT[b][k] = (kg < Dd) ? xt[(size_t)b * (Ll * Dd) + kg] : h[b * Dd + kg - Dd];
        }
        #pragma unroll
        for (int i = 0; i < 8; ++i){
            int idx = tid + i * 256;
            int k = idx >> 5, j = idx & 31;
            int kg = k0 + kk + k;
            wT[k][j] = (kg < Dd) ? Wr[(size_t)kg * G4 + j0 + j] : Ur[(size_t)(kg - Dd) * G4 + j0 + j];
        }
        __syncthreads();
        #pragma unroll 8
        for (int k = 0; k < 64; ++k){
            float4 wv = *(const float4*)&wT[k][tj4];
            float i0 = inT[tb][k];
            float i1 = inT[tb + 32][k];
            a00 = fmaf(i0, wv.x, a00); a01 = fmaf(i0, wv.y, a01);
            a02 = fmaf(i0, wv.z, a02); a03 = fmaf(i0, wv.w, a03);
            a10 = fmaf(i1, wv.x, a10); a11 = fmaf(i1, wv.y, a11);
            a12 = fmaf(i1, wv.z, a12); a13 = fmaf(i1, wv.w, a13);
        }
        __syncthreads();
    }
    size_t o0 = (size_t)(ks * Bb + tb) * G4 + j0 + tj4;
    size_t o1 = (size_t)(ks * Bb + tb + 32) * G4 + j0 + tj4;
    *(float4*)&part[o0] = make_float4(a00, a01, a02, a03);
    *(float4*)&part[o1] = make_float4(a10, a11, a12, a13);
}

// ---------------- FUSED GEMM: blocks [0,256) = writer(t), [256,512) = reader(t+1) ----------------
__global__ __launch_bounds__(256) void gemm_both(const float* __restrict__ o, const float* __restrict__ mrt,
                                                 const float* __restrict__ hw, const float* __restrict__ Wf,
                                                 float* __restrict__ partW,
                                                 const float* __restrict__ xt1, const float* __restrict__ Wr,
                                                 const float* __restrict__ Ur, float* __restrict__ partR){
    __shared__ float inT[64][65];
    __shared__ float wT[64][32];
    const int bxg = blockIdx.x;
    const int writer = (bxg < 256) ? 1 : 0;
    const int bx = writer ? bxg : bxg - 256;
    const int jt = bx & 63, ks = bx >> 6;
    const int j0 = jt * 32;
    const int tid = threadIdx.x;
    const int tj4 = (tid & 7) * 4;
    const int tb  = tid >> 3;
    float a00=0.f,a01=0.f,a02=0.f,a03=0.f;
    float a10=0.f,a11=0.f,a12=0.f,a13=0.f;
    const int KC = writer ? 384 : 256;
    const int k0 = ks * KC;
    for (int kk = 0; kk < KC; kk += 64){
        #pragma unroll
        for (int i = 0; i < 16; ++i){
            int idx = tid + i * 256;
            int b = idx >> 6, k = idx & 63;
            int kg = k0 + kk + k;
            float v;
            if (writer){
                if (kg < Dd)           v = o[b * Dd + kg];
                else if (kg < 2 * Dd)  v = mrt[b * Dd + kg - Dd];
                else                   v = hw[b * Dd + kg - 2 * Dd];
            } else {
                v = (kg < Dd) ? xt1[(size_t)b * (Ll * Dd) + kg] : o[b * Dd + kg - Dd];
            }
            inT[b][k] = v;
        }
        #pragma unroll
        for (int i = 0; i < 8; ++i){
            int idx = tid + i * 256;
            int k = idx >> 5, j = idx & 31;
            int kg = k0 + kk + k;
            float v;
            if (writer) v = Wf[(size_t)kg * G4 + j0 + j];
            else        v = (kg < Dd) ? Wr[(size_t)kg * G4 + j0 + j] : Ur[(size_t)(kg - Dd) * G4 + j0 + j];
            wT[k][j] = v;
        }
        __syncthreads();
        #pragma unroll 8
        for (int k = 0; k < 64; ++k){
            float4 wv = *(const float4*)&wT[k][tj4];
            float i0 = inT[tb][k];
            float i1 = inT[tb + 32][k];
            a00 = fmaf(i0, wv.x, a00); a01 = fmaf(i0, wv.y, a01);
            a02 = fmaf(i0, wv.z, a02); a03 = fmaf(i0, wv.w, a03);
            a10 = fmaf(i1, wv.x, a10); a11 = fmaf(i1, wv.y, a11);
            a12 = fmaf(i1, wv.z, a12); a13 = fmaf(i1, wv.w, a13);
        }
        __syncthreads();
    }
    float* part = writer ? partW : partR;
    size_t o0 = (size_t)(ks * Bb + tb) * G4 + j0 + tj4;
    size_t o1 = (size_t)(ks * Bb + tb + 32) * G4 + j0 + tj4;
    *(float4*)&part[o0] = make_float4(a00, a01, a02, a03);
    *(float4*)&part[o1] = make_float4(a10, a11, a12, a13);
}

// ---------------- final writer pw (once, after the loop) ----------------
__global__ __launch_bounds__(256) void pw_final(const float* __restrict__ partW, const float* __restrict__ bfv,
                                                const float* __restrict__ cwOld, float* __restrict__ out){
    int idx = blockIdx.x * 256 + threadIdx.x;
    int b = idx >> 9, d = idx & 511;
    float z[4];
    #pragma unroll
    for (int g = 0; g < 4; ++g){
        int j = g * Dd + d;
        float s = bfv[j];
        #pragma unroll
        for (int ks = 0; ks < 4; ++ks) s += partW[(size_t)(ks * Bb + b) * G4 + j];
        z[g] = s;
    }
    float i = hsig(z[0]), f = hsig(z[1]), g2 = tanhf(z[2]), o = hsig(z[3]);
    float cn = fmaf(f, cwOld[idx], i * g2);
    out[idx] = o * tanhf(cn);
}

// ---------------- MEGA2: pw-prologue (reader t, writer t-1) + update(t-1) + scores(t) + read ----------------
// grid 1024 = 64 b x 16 lb, block 256 (4 waves). Wave owns 16 rows as TWO interleaved streams.
// mode: 0 = t==0 (reader pw only; no writer/update), 1 = t==1 (forced full write), 2 = t>=2 (skippable)
__global__ __launch_bounds__(256, 4) void mega2(const float* __restrict__ memIn, float* __restrict__ memOut,
                                                const float* __restrict__ partR, const float* __restrict__ br,
                                                const float* __restrict__ crOld, float* __restrict__ crNew,
                                                float* __restrict__ h_r,
                                                const float* __restrict__ partW, const float* __restrict__ bfv,
                                                const float* __restrict__ cwOld, float* __restrict__ cwNew,
                                                float* __restrict__ hwOut,
                                                float* __restrict__ scores, const float* __restrict__ Mb,
                                                const float* __restrict__ Sinv,
                                                float* __restrict__ part, int mode){
    __shared__ float o_lds[512];
    __shared__ float hw_lds[512];
    const int bid = blockIdx.x;
    const int b = bid >> 4, lb = bid & 15;
    const int tid = threadIdx.x;

    // ---- per-block pw prologue: compute o_t and hw_{t-1} for this b (once per block, into LDS) ----
    #pragma unroll
    for (int pass = 0; pass < 2; ++pass){
        const int d = tid + pass * 256;
        // reader pw (step t)
        float z0 = br[d], z1 = br[Dd + d], z2 = br[2 * Dd + d], z3 = br[3 * Dd + d];
        #pragma unroll
        for (int ks = 0; ks < 4; ++ks){
            const float* p = partR + (size_t)(ks * Bb + b) * G4;
            z0 += p[d]; z1 += p[Dd + d]; z2 += p[2 * Dd + d]; z3 += p[3 * Dd + d];
        }
        float ri = hsig(z0), rf = hsig(z1), rg = tanhf(z2), ro = hsig(z3);
        float rcn = fmaf(rf, crOld[b * Dd + d], ri * rg);
        float rhn = ro * tanhf(rcn);
        o_lds[d] = rhn;
        if (lb == 0){ crNew[b * Dd + d] = rcn; h_r[b * Dd + d] = rhn; }
        // writer pw (step t-1)
        if (mode){
            float w0 = bfv[d], w1 = bfv[Dd + d], w2 = bfv[2 * Dd + d], w3 = bfv[3 * Dd + d];
            #pragma unroll
            for (int ks = 0; ks < 4; ++ks){
                const float* p = partW + (size_t)(ks * Bb + b) * G4;
                w0 += p[d]; w1 += p[Dd + d]; w2 += p[2 * Dd + d]; w3 += p[3 * Dd + d];
            }
            float wi = hsig(w0), wf = hsig(w1), wg = tanhf(w2), wo = hsig(w3);
            float wcn = fmaf(wf, cwOld[b * Dd + d], wi * wg);
            float whn = wo * tanhf(wcn);
            hw_lds[d] = whn;
            if (lb == 0){ cwNew[b * Dd + d] = wcn; hwOut[b * Dd + d] = whn; }
        } else {
            hw_lds[d] = 0.f;
        }
    }
    __syncthreads();

    const int lane = tid & 63;
    const int gw = lb * 4 + (tid >> 6);     // 0..63
    const int d0 = lane * 4, d1 = 256 + lane * 4;
    float4 oa  = *(const float4*)&o_lds[d0];
    float4 obv = *(const float4*)&o_lds[d1];
    float4 ha  = *(const float4*)&hw_lds[d0];
    float4 hb  = *(const float4*)&hw_lds[d1];

    const int lbase = gw * 16;
    float* srow = scores + b * Ll;

    // ---- zp precompute: lane r<16 holds zp for row lbase+r (mode >= 1) ----
    float zpv = 0.f;
    if (mode && lane < 16) zpv = __expf(srow[lbase + lane] - Mb[b]) * Sinv[b];

    float mA = -INFINITY, sAs = 0.f, mB = -INFINITY, sBs = 0.f;
    float A0x=0.f,A0y=0.f,A0z=0.f,A0w=0.f, A1x=0.f,A1y=0.f,A1z=0.f,A1w=0.f;
    float B0x=0.f,B0y=0.f,B0z=0.f,B0w=0.f, B1x=0.f,B1y=0.f,B1z=0.f,B1w=0.f;
    size_t baseA = ((size_t)b * Ll + lbase) * Dd;
    size_t baseB = baseA + (size_t)8 * Dd;
    #pragma unroll 2
    for (int r = 0; r < 8; ++r){
        float4 vA0 = *(const float4*)(memIn + baseA + d0);
        float4 vA1 = *(const float4*)(memIn + baseA + d1);
        float4 vB0 = *(const float4*)(memIn + baseB + d0);
        float4 vB1 = *(const float4*)(memIn + baseB + d1);
        if (mode){
            float zpA = __shfl(zpv, r);
            float zpB = __shfl(zpv, 8 + r);
            float omA = 1.f - zpA, omB = 1.f - zpB;
            vA0.x = fmaf(vA0.x, omA, ha.x * zpA); vA0.y = fmaf(vA0.y, omA, ha.y * zpA);
            vA0.z = fmaf(vA0.z, omA, ha.z * zpA); vA0.w = fmaf(vA0.w, omA, ha.w * zpA);
            vA1.x = fmaf(vA1.x, omA, hb.x * zpA); vA1.y = fmaf(vA1.y, omA, hb.y * zpA);
            vA1.z = fmaf(vA1.z, omA, hb.z * zpA); vA1.w = fmaf(vA1.w, omA, hb.w * zpA);
            vB0.x = fmaf(vB0.x, omB, ha.x * zpB); vB0.y = fmaf(vB0.y, omB, ha.y * zpB);
            vB0.z = fmaf(vB0.z, omB, ha.z * zpB); vB0.w = fmaf(vB0.w, omB, ha.w * zpB);
            vB1.x = fmaf(vB1.x, omB, hb.x * zpB); vB1.y = fmaf(vB1.y, omB, hb.y * zpB);
            vB1.z = fmaf(vB1.z, omB, hb.z * zpB); vB1.w = fmaf(vB1.w, omB, hb.w * zpB);
            if (mode == 1 || zpA > 1e-7f){
                *(float4*)(memOut + baseA + d0) = vA0;
                *(float4*)(memOut + baseA + d1) = vA1;
            }
            if (mode == 1 || zpB > 1e-7f){
                *(float4*)(memOut + baseB + d0) = vB0;
                *(float4*)(memOut + baseB + d1) = vB1;
            }
        }
        float sa = vA0.x*oa.x + vA0.y*oa.y + vA0.z*oa.z + vA0.w*oa.w
                 + vA1.x*obv.x + vA1.y*obv.y + vA1.z*obv.z + vA1.w*obv.w;
        float sb = vB0.x*oa.x + vB0.y*oa.y + vB0.z*oa.z + vB0.w*oa.w
                 + vB1.x*obv.x + vB1.y*obv.y + vB1.z*obv.z + vB1.w*obv.w;
        #pragma unroll
        for (int off = 32; off; off >>= 1){
            sa += __shfl_xor(sa, off);
            sb += __shfl_xor(sb, off);
        }
        if (lane == 0){ srow[lbase + r] = sa; srow[lbase + 8 + r] = sb; }
        float nmA = fmaxf(mA, sa);
        float scA = __expf(mA - nmA);
        float wtA = __expf(sa - nmA);
        sAs = fmaf(sAs, scA, wtA);
        A0x = fmaf(A0x, scA, vA0.x * wtA); A0y = fmaf(A0y, scA, vA0.y * wtA);
        A0z = fmaf(A0z, scA, vA0.z * wtA); A0w = fmaf(A0w, scA, vA0.w * wtA);
        A1x = fmaf(A1x, scA, vA1.x * wtA); A1y = fmaf(A1y, scA, vA1.y * wtA);
        A1z = fmaf(A1z, scA, vA1.z * wtA); A1w = fmaf(A1w, scA, vA1.w * wtA);
        mA = nmA;
        float nmB = fmaxf(mB, sb);
        float scB = __expf(mB - nmB);
        float wtB = __expf(sb - nmB);
        sBs = fmaf(sBs, scB, wtB);
        B0x = fmaf(B0x, scB, vB0.x * wtB); B0y = fmaf(B0y, scB, vB0.y * wtB);
        B0z = fmaf(B0z, scB, vB0.z * wtB); B0w = fmaf(B0w, scB, vB0.w * wtB);
        B1x = fmaf(B1x, scB, vB1.x * wtB); B1y = fmaf(B1y, scB, vB1.y * wtB);
        B1z = fmaf(B1z, scB, vB1.z * wtB); B1w = fmaf(B1w, scB, vB1.w * wtB);
        mB = nmB;
        baseA += Dd; baseB += Dd;
    }
    float M = fmaxf(mA, mB);
    float eA = __expf(mA - M), eB = __expf(mB - M);
    float ssum = sAs * eA + sBs * eB;
    float* p = part + (size_t)(b * 64 + gw) * PART_STRIDE;
    *(float4*)(p + d0) = make_float4(A0x * eA + B0x * eB, A0y * eA + B0y * eB,
                                     A0z * eA + B0z * eB, A0w * eA + B0w * eB);
    *(float4*)(p + d1) = make_float4(A1x * eA + B1x * eB, A1y * eA + B1y * eB,
                                     A1z * eA + B1z * eB, A1w * eA + B1w * eB);
    if (lane == 0){ p[512] = M; p[513] = ssum; }
}

// ---------------- finalize: combine 64 wave partials per b -> m_rt, M, 1/S ----------------
__global__ __launch_bounds__(256) void small_a(const float* __restrict__ part, float* __restrict__ mrt,
                                               float* __restrict__ Mb, float* __restrict__ Sinv){
    const int b = blockIdx.x >> 2, dseg = blockIdx.x & 3;
    const int tid = threadIdx.x;
    __shared__ float ews[64];
    __shared__ float psum[256];
    if (tid < 64){
        const float* pp = part + (size_t)(b * 64 + tid) * PART_STRIDE;
        float mw = pp[512], sw = pp[513];
        float M = mw;
        #pragma unroll
        for (int off = 32; off; off >>= 1) M = fmaxf(M, __shfl_xor(M, off));
        float e = __expf(mw - M);
        float Ssum = sw * e;
        #pragma unroll
        for (int off = 32; off; off >>= 1) Ssum += __shfl_xor(Ssum, off);
        float Si = 1.f / Ssum;
        ews[tid] = e * Si;
        if (dseg == 0 && tid == 0){ Mb[b] = M; Sinv[b] = Si; }
    }
    __syncthreads();
    const int dl = tid & 127, half = tid >> 7;
    const int d = dseg * 128 + dl;
    const float* pb = part + (size_t)(b * 64 + half * 32) * PART_STRIDE + d;
    float s = 0.f;
    #pragma unroll 8
    for (int w2 = 0; w2 < 32; ++w2)
        s = fmaf(pb[(size_t)w2 * PART_STRIDE], ews[half * 32 + w2], s);
    psum[tid] = s;
    __syncthreads();
    if (half == 0) mrt[b * Dd + d] = psum[tid] + psum[tid + 128];
}

extern "C" void kernel_launch(void* const* d_in, const int* in_sizes, int n_in,
                              void* d_out, int out_size, void* d_ws, size_t ws_size,
                              hipStream_t stream) {
    (void)in_sizes; (void)n_in; (void)out_size;
    const float* x  = (const float*)d_in[0];
    const float* Wr = (const float*)d_in[1];
    const float* Ur = (const float*)d_in[2];
    const float* br = (const float*)d_in[3];
    const float* Ww = (const float*)d_in[4];
    const float* Uw = (const float*)d_in[5];
    const float* bw = (const float*)d_in[6];
    const float* Wc = (const float*)d_in[7];
    const float* bc = (const float*)d_in[8];
    float* out = (float*)d_out;

    float* w = (float*)d_ws;
    float* mem     = w; w += (size_t)Bb * Ll * Dd;            // 134 MB fp32
    float* scores  = w; w += (size_t)Bb * Ll;
    float* part_me = w; w += (size_t)Bb * 64 * PART_STRIDE;   // ~8.5 MB
    float* Mb      = w; w += 64;
    float* Sinv    = w; w += 64;
    float* mrt     = w; w += (size_t)Bb * Dd;
    float* h_r     = w; w += (size_t)Bb * Dd;     // memset region: h_r,hw,cr0,cr1,cw0,cw1
    float* hw      = w; w += (size_t)Bb * Dd;
    float* cr0     = w; w += (size_t)Bb * Dd;
    float* cr1     = w; w += (size_t)Bb * Dd;
    float* cw0     = w; w += (size_t)Bb * Dd;
    float* cw1     = w; w += (size_t)Bb * Dd;
    float* partR   = w; w += (size_t)4 * Bb * G4;
    float* partW   = w; w += (size_t)4 * Bb * G4;
    float* Wf      = w; w += (size_t)1536 * G4;
    float* bf      = w; w += G4;
    size_t need = (size_t)(w - (float*)d_ws) * sizeof(float);
    if (ws_size < need) return;

    hipMemsetAsync(h_r, 0, (size_t)6 * Bb * Dd * sizeof(float), stream);
    wf_build<<<(1536 / 16) * 8, 256, 0, stream>>>(Wc, Ww, Uw, Wf);
    bf_build<<<G4 / 256, 256, 0, stream>>>(bc, Ww, bw, bf);

    // prologue: reader gate GEMM for step 0 (h_r = 0); mega2(0) does reader_pw(0)
    gemm_reader<<<256, 256, 0, stream>>>(x, h_r, Wr, Ur, partR);

    float* crbuf[2] = { cr0, cr1 };
    float* cwbuf[2] = { cw0, cw1 };
    for (int t = 0; t < Ll; ++t){
        const float* mi = (t <= 1) ? x : mem;   // mem fully valid after t==1's forced write
        int mode = (t == 0) ? 0 : ((t == 1) ? 1 : 2);
        int p = t & 1;
        // mega2: reader_pw(t) [reads crbuf[p^1], writes crbuf[p]],
        //        writer_pw(t-1) [reads cwbuf[p], writes cwbuf[p^1]],
        //        update(t-1) + scores(t) + online-softmax partials
        mega2<<<1024, 256, 0, stream>>>(mi, mem,
                                        partR, br, crbuf[p ^ 1], crbuf[p], h_r,
                                        partW, bf, cwbuf[p], cwbuf[p ^ 1], hw,
                                        scores, Mb, Sinv, part_me, mode);
        small_a<<<256, 256, 0, stream>>>(part_me, mrt, Mb, Sinv);
        int tn = (t + 1 < Ll) ? t + 1 : t;      // last-step reader gates are unused
        gemm_both<<<512, 256, 0, stream>>>(h_r, mrt, hw, Wf, partW,
                                           x + (size_t)tn * Dd, Wr, Ur, partR);
    }
    // final writer pw: step Ll-1 uses cw(Ll-2), which lives in cwbuf[((Ll-1)&1)^1] = cwbuf[0]
    pw_final<<<128, 256, 0, stream>>>(partW, bf, cwbuf[0], out);
}